// Round 5
// baseline (269.356 us; speedup 1.0000x reference)
//
#include <hip/hip_runtime.h>
#include <hip/hip_bf16.h>
#include <math.h>

// Problem constants (fixed by the reference)
#define NN 129
#define FF 262144
#define EE 16384
#define CHUNKS 32
#define CHUNK (FF / CHUNKS)   // 8192 floats per matvec block
#define NB 64                 // tail-kernel blocks (1 edge per thread)
#define EPB (EE / NB)         // 256 edges per block

// ws layout (doubles)
#define OFF_PARTIAL 0                              // [NN*CHUNKS] = 4128
#define OFF_DEGP    (OFF_PARTIAL + NN*CHUNKS)      // [NB*3*NN]
#define OFF_H1P     (OFF_DEGP + NB*3*NN)           // [NB*3*NN]
#define OFF_H2P     (OFF_H1P + NB*3*NN)            // [NB*3*NN]
#define OFF_BAR     (OFF_H2P + NB*3*NN)            // 2 uints (in a double slot)

typedef float vfloat4 __attribute__((ext_vector_type(4)));

// ---------------------------------------------------------------------------
// K1: matvec partials (4128 blocks) + NB blocks of per-block degree partials.
// x streamed with NON-TEMPORAL loads so the 135 MB stream doesn't evict W
// (1 MB, reused 129x) from the per-XCD L2s.
// ---------------------------------------------------------------------------
__global__ __launch_bounds__(256) void k_matvec(
    const float* __restrict__ x, const float* __restrict__ W,
    const int* __restrict__ eidx, const float* __restrict__ eattr,
    double* __restrict__ ws)
{
    const int b = blockIdx.x;
    const int tid = threadIdx.x;
    const int wave = tid >> 6, lane = tid & 63;

    __shared__ double ws4[4];
    __shared__ double dp[4][3][NN];

    if (b < NN * CHUNKS) {
        const int r = b / CHUNKS, ch = b % CHUNKS;
        const vfloat4* xp = (const vfloat4*)(x + (size_t)r * FF + (size_t)ch * CHUNK);
        const float4*  wp = (const float4*)(W + (size_t)ch * CHUNK);
        double acc0 = 0.0, acc1 = 0.0;
#pragma unroll
        for (int i = 0; i < CHUNK / (256 * 4); ++i) {   // 8 iters
            vfloat4 xv = __builtin_nontemporal_load(xp + tid + i * 256);  // nt: bypass L2 allocate
            float4  wv = wp[tid + i * 256];                               // normal: stay L2-hot
            acc0 += (double)xv[0] * (double)wv.x + (double)xv[1] * (double)wv.y;
            acc1 += (double)xv[2] * (double)wv.z + (double)xv[3] * (double)wv.w;
        }
        double acc = acc0 + acc1;
        for (int off = 32; off > 0; off >>= 1) acc += __shfl_down(acc, off, 64);
        if (lane == 0) ws4[wave] = acc;
        __syncthreads();
        if (tid == 0) ws[OFF_PARTIAL + b] = (ws4[0] + ws4[1]) + (ws4[2] + ws4[3]);
    } else {
        const int bb = b - NN * CHUNKS;                 // [0, NB)
        if (bb == 0 && tid == 0) {
            unsigned* bar = (unsigned*)(ws + OFF_BAR);
            __hip_atomic_store(&bar[0], 0u, __ATOMIC_RELAXED, __HIP_MEMORY_SCOPE_AGENT);
            __hip_atomic_store(&bar[1], 0u, __ATOMIC_RELAXED, __HIP_MEMORY_SCOPE_AGENT);
        }
        // one edge per thread
        const int e = bb * EPB + tid;
        const int cl = eidx[EE + e];
        const float a0 = eattr[e * 3 + 0], a1 = eattr[e * 3 + 1], a2 = eattr[e * 3 + 2];
        for (int i = tid; i < 4 * 3 * NN; i += 256) ((double*)dp)[i] = 0.0;
        __syncthreads();
        unsafeAtomicAdd(&dp[wave][0][cl], (double)a0);
        unsafeAtomicAdd(&dp[wave][1][cl], (double)a1);
        unsafeAtomicAdd(&dp[wave][2][cl], (double)a2);
        __syncthreads();
        for (int i = tid; i < 3 * NN; i += 256) {
            const int c = i / NN, j = i % NN;
            ws[OFF_DEGP + bb * (3 * NN) + i] =
                (dp[0][c][j] + dp[1][c][j]) + (dp[2][c][j] + dp[3][c][j]);
        }
    }
}

// ---------------------------------------------------------------------------
// Device-scope barrier for NB co-resident blocks (counters zeroed by K1).
// ---------------------------------------------------------------------------
__device__ __forceinline__ void gbar(unsigned* bar, int idx) {
    __syncthreads();
    if (threadIdx.x == 0) {
        __threadfence();
        __hip_atomic_fetch_add(&bar[idx], 1u, __ATOMIC_ACQ_REL, __HIP_MEMORY_SCOPE_AGENT);
        while (__hip_atomic_load(&bar[idx], __ATOMIC_ACQUIRE, __HIP_MEMORY_SCOPE_AGENT) < (unsigned)NB)
            __builtin_amdgcn_s_sleep(1);
        __threadfence();
    }
    __syncthreads();
}

// ---------------------------------------------------------------------------
// K2 (NB=64 blocks, 1 edge/thread, manual grid barriers): rest of network.
// Separate kernel ON PURPOSE: its ~55 KB LDS would cap the streaming matvec
// at 2 blocks/CU if fused.
// ---------------------------------------------------------------------------
__global__ __launch_bounds__(256) void k_rest(
    const int* __restrict__ eidx, const float* __restrict__ eattr,
    double* __restrict__ ws,
    const float* __restrict__ b1, const float* __restrict__ W2, const float* __restrict__ b2,
    const float* __restrict__ c1w, const float* __restrict__ c1b,
    const float* __restrict__ c2w, const float* __restrict__ c2b,
    const float* __restrict__ f1W, const float* __restrict__ f1b,
    const float* __restrict__ f2W, const float* __restrict__ f2b,
    const float* __restrict__ f3W, const float* __restrict__ f3b,
    float* __restrict__ out)
{
    __shared__ double sxw[NN];
    __shared__ double sdinv[3][NN];
    __shared__ double sh1[3][NN];
    __shared__ double hp[4][3][NN];
    // final-phase (block 0 only)
    __shared__ double h2f[3][NN];
    __shared__ double z0[3][NN], z1[3][NN];
    __shared__ int    rnk[3][NN];
    __shared__ double c1o[3][3][127];
    __shared__ double p1o[3][3][125];
    __shared__ double c2o[3][123];
    __shared__ double allx[363];
    __shared__ double fc1o[32], fc2o[6];

    const int b = blockIdx.x, tid = threadIdx.x, wave = tid >> 6;
    unsigned* bar = (unsigned*)(ws + OFF_BAR);

    // ---- Prefetch this thread's edge record FIRST: the cold-miss latency
    // overlaps the phase-0 partial reductions below.
    const int e = b * EPB + tid;
    const int er = eidx[e];
    const int ec = eidx[EE + e];
    const float ea0 = eattr[e * 3 + 0];
    const float ea1 = eattr[e * 3 + 1];
    const float ea2 = eattr[e * 3 + 2];

    // ---- Phase 0: xw + dinv (redundant per block; L2-warm reads)
    for (int j = tid; j < NN; j += 256) {
        double s = 0.0;
#pragma unroll
        for (int k = 0; k < CHUNKS; ++k) s += ws[OFF_PARTIAL + j * CHUNKS + k];
        sxw[j] = s;
    }
    for (int v = tid; v < 3 * NN; v += 256) {
        double d = 1.0;                                  // self loop weight
        for (int k = 0; k < NB; ++k) d += ws[OFF_DEGP + k * (3 * NN) + v];
        ((double*)sdinv)[v] = (d > 0.0) ? 1.0 / sqrt(d) : 0.0;
    }
    for (int i = tid; i < 4 * 3 * NN; i += 256) ((double*)hp)[i] = 0.0;
    __syncthreads();

    // ---- Phase 1: layer-1 aggregation (1 edge/thread; norms cached in regs)
    double nw0 = sdinv[0][er] * (double)ea0 * sdinv[0][ec];
    double nw1 = sdinv[1][er] * (double)ea1 * sdinv[1][ec];
    double nw2 = sdinv[2][er] * (double)ea2 * sdinv[2][ec];
    {
        const double xwr = sxw[er];
        unsafeAtomicAdd(&hp[wave][0][ec], nw0 * xwr);
        unsafeAtomicAdd(&hp[wave][1][ec], nw1 * xwr);
        unsafeAtomicAdd(&hp[wave][2][ec], nw2 * xwr);
    }
    __syncthreads();
    for (int i = tid; i < 3 * NN; i += 256) {
        const int c = i / NN, j = i % NN;
        ws[OFF_H1P + b * (3 * NN) + i] =
            (hp[0][c][j] + hp[1][c][j]) + (hp[2][c][j] + hp[3][c][j]);
    }
    gbar(bar, 0);

    // ---- Phase 2: h1 (redundant per block)
    const double bb1 = (double)b1[0];
    for (int i = tid; i < 3 * NN; i += 256) {
        const int j = i % NN;
        const double dv = ((double*)sdinv)[i];
        double s = dv * dv * sxw[j] + bb1;
        for (int k = 0; k < NB; ++k) s += ws[OFF_H1P + k * (3 * NN) + i];
        ((double*)sh1)[i] = s;
    }
    for (int i = tid; i < 4 * 3 * NN; i += 256) ((double*)hp)[i] = 0.0;
    __syncthreads();

    // ---- Phase 3: layer-2 aggregation (same edges; register-cached norms)
    const double w2 = (double)W2[0];
    unsafeAtomicAdd(&hp[wave][0][ec], nw0 * (sh1[0][er] * w2));
    unsafeAtomicAdd(&hp[wave][1][ec], nw1 * (sh1[1][er] * w2));
    unsafeAtomicAdd(&hp[wave][2][ec], nw2 * (sh1[2][er] * w2));
    __syncthreads();
    for (int i = tid; i < 3 * NN; i += 256) {
        const int c = i / NN, j = i % NN;
        ws[OFF_H2P + b * (3 * NN) + i] =
            (hp[0][c][j] + hp[1][c][j]) + (hp[2][c][j] + hp[3][c][j]);
    }
    gbar(bar, 1);

    // ---- Phase 4: block 0 finishes the network
    if (b != 0) return;

    const double bb2 = (double)b2[0];
    for (int i = tid; i < 3 * NN; i += 256) {
        const int j = i % NN;
        const double dv = ((double*)sdinv)[i];
        double s = dv * dv * (((double*)sh1)[i] * w2) + bb2;
        for (int k = 0; k < NB; ++k) s += ws[OFF_H2P + k * (3 * NN) + i];
        ((double*)h2f)[i] = s;
    }
    __syncthreads();

    // SortPool: stable argsort of -h2 (descending, ties by index), k = N
    for (int i = tid; i < 3 * NN; i += 256) {
        const int c = i / NN, j = i % NN;
        const double v = h2f[c][j];
        int rk = 0;
        for (int q = 0; q < NN; ++q) {
            const double u = h2f[c][q];
            rk += (u > v) || (u == v && q < j);
        }
        rnk[c][j] = rk;
    }
    __syncthreads();
    for (int i = tid; i < 3 * NN; i += 256) {
        const int c = i / NN, j = i % NN;
        const int rk = rnk[c][j];
        z0[c][rk] = sh1[c][j];
        z1[c][rk] = h2f[c][j];
    }
    __syncthreads();

    // conv1 (in=2,out=3,k=3, VALID) -> 127
    for (int i = tid; i < 3 * 3 * 127; i += 256) {
        const int c = i / (3 * 127), rem = i % (3 * 127), o = rem / 127, p = rem % 127;
        double s = (double)c1b[o];
#pragma unroll
        for (int k = 0; k < 3; ++k) {
            s += (double)c1w[(o * 2 + 0) * 3 + k] * z0[c][p + k];
            s += (double)c1w[(o * 2 + 1) * 3 + k] * z1[c][p + k];
        }
        c1o[c][o][p] = s;
    }
    __syncthreads();
    for (int i = tid; i < 3 * 3 * 125; i += 256) {
        const int c = i / (3 * 125), rem = i % (3 * 125), o = rem / 125, p = rem % 125;
        p1o[c][o][p] = fmax(c1o[c][o][p], fmax(c1o[c][o][p + 1], c1o[c][o][p + 2]));
    }
    __syncthreads();
    for (int i = tid; i < 3 * 123; i += 256) {
        const int c = i / 123, p = i % 123;
        double s = (double)c2b[0];
#pragma unroll
        for (int ic = 0; ic < 3; ++ic)
#pragma unroll
            for (int k = 0; k < 3; ++k)
                s += (double)c2w[ic * 3 + k] * p1o[c][ic][p + k];
        c2o[c][p] = s;
    }
    __syncthreads();
    for (int i = tid; i < 3 * 121; i += 256) {
        const int c = i / 121, p = i % 121;
        allx[c * 121 + p] = fmax(c2o[c][p], fmax(c2o[c][p + 1], c2o[c][p + 2]));
    }
    __syncthreads();

    // fc1: 363 -> 32, ELU (8 lanes per output, aligned subgroups)
    {
        const int j = tid >> 3, t = tid & 7;
        double s = 0.0;
        for (int i = t; i < 363; i += 8) s += allx[i] * (double)f1W[i * 32 + j];
        s += __shfl_down(s, 4, 8);
        s += __shfl_down(s, 2, 8);
        s += __shfl_down(s, 1, 8);
        if (t == 0) {
            s += (double)f1b[j];
            fc1o[j] = (s > 0.0) ? s : expm1(s);
        }
    }
    __syncthreads();
    if (tid < 6) {
        double s = (double)f2b[tid];
        for (int i = 0; i < 32; ++i) s += fc1o[i] * (double)f2W[i * 6 + tid];
        fc2o[tid] = (s > 0.0) ? s : expm1(s);
    }
    __syncthreads();
    if (tid < 2) {
        double s = (double)f3b[tid];
        for (int i = 0; i < 6; ++i) s += fc2o[i] * (double)f3W[i * 2 + tid];
        out[tid] = (float)s;
    }
}

extern "C" void kernel_launch(void* const* d_in, const int* in_sizes, int n_in,
                              void* d_out, int out_size, void* d_ws, size_t ws_size,
                              hipStream_t stream) {
    const float* x    = (const float*)d_in[0];
    const int*   eidx = (const int*)d_in[1];
    const float* eattr= (const float*)d_in[2];
    const float* g1W  = (const float*)d_in[3];
    const float* g1b  = (const float*)d_in[4];
    const float* g2W  = (const float*)d_in[5];
    const float* g2b  = (const float*)d_in[6];
    const float* c1w  = (const float*)d_in[7];
    const float* c1b  = (const float*)d_in[8];
    const float* c2w  = (const float*)d_in[9];
    const float* c2b  = (const float*)d_in[10];
    const float* f1W  = (const float*)d_in[11];
    const float* f1b  = (const float*)d_in[12];
    const float* f2W  = (const float*)d_in[13];
    const float* f2b  = (const float*)d_in[14];
    const float* f3W  = (const float*)d_in[15];
    const float* f3b  = (const float*)d_in[16];
    float* out = (float*)d_out;
    double* ws = (double*)d_ws;

    k_matvec<<<NN * CHUNKS + NB, 256, 0, stream>>>(x, g1W, eidx, eattr, ws);
    k_rest<<<NB, 256, 0, stream>>>(eidx, eattr, ws,
                                   g1b, g2W, g2b, c1w, c1b, c2w, c2b,
                                   f1W, f1b, f2W, f2b, f3W, f3b, out);
}

// Round 6
// 255.821 us; speedup vs baseline: 1.0529x; 1.0529x over previous
//
#include <hip/hip_runtime.h>
#include <hip/hip_bf16.h>
#include <math.h>

// Problem constants (fixed by the reference)
#define NN 129
#define FF 262144
#define EE 16384
#define CHUNKS 32
#define CHUNK (FF / CHUNKS)   // 8192 floats per matvec block
#define NB 16                 // tail blocks: a*NB (reduction) + b/NB (atomics) min near 16
#define EPB (EE / NB)         // 1024 edges per block
#define EPT (EPB / 256)       // 4 edges per thread

// ws layout (doubles)
#define OFF_PARTIAL 0                              // [NN*CHUNKS] = 4128
#define OFF_DEGP    (OFF_PARTIAL + NN*CHUNKS)      // [NB*3*NN]
#define OFF_H1P     (OFF_DEGP + NB*3*NN)           // [NB*3*NN]
#define OFF_H2P     (OFF_H1P + NB*3*NN)            // [NB*3*NN]
#define OFF_BAR     (OFF_H2P + NB*3*NN)            // 2 uints (in a double slot)

typedef float vfloat4 __attribute__((ext_vector_type(4)));

// ---------------------------------------------------------------------------
// K1: matvec partials (4128 blocks) + NB blocks of per-block degree partials.
// x streamed with NON-TEMPORAL loads so the 135 MB stream doesn't evict W
// (1 MB, reused 129x) from the per-XCD L2s (measured −9 µs in R4).
// ---------------------------------------------------------------------------
__global__ __launch_bounds__(256) void k_matvec(
    const float* __restrict__ x, const float* __restrict__ W,
    const int* __restrict__ eidx, const float* __restrict__ eattr,
    double* __restrict__ ws)
{
    const int b = blockIdx.x;
    const int tid = threadIdx.x;
    const int wave = tid >> 6, lane = tid & 63;

    __shared__ double ws4[4];
    __shared__ double dp[4][3][NN];

    if (b < NN * CHUNKS) {
        const int r = b / CHUNKS, ch = b % CHUNKS;
        const vfloat4* xp = (const vfloat4*)(x + (size_t)r * FF + (size_t)ch * CHUNK);
        const float4*  wp = (const float4*)(W + (size_t)ch * CHUNK);
        double acc0 = 0.0, acc1 = 0.0;
#pragma unroll
        for (int i = 0; i < CHUNK / (256 * 4); ++i) {   // 8 iters
            vfloat4 xv = __builtin_nontemporal_load(xp + tid + i * 256);  // nt: bypass L2 allocate
            float4  wv = wp[tid + i * 256];                               // normal: stay L2-hot
            acc0 += (double)xv[0] * (double)wv.x + (double)xv[1] * (double)wv.y;
            acc1 += (double)xv[2] * (double)wv.z + (double)xv[3] * (double)wv.w;
        }
        double acc = acc0 + acc1;
        for (int off = 32; off > 0; off >>= 1) acc += __shfl_down(acc, off, 64);
        if (lane == 0) ws4[wave] = acc;
        __syncthreads();
        if (tid == 0) ws[OFF_PARTIAL + b] = (ws4[0] + ws4[1]) + (ws4[2] + ws4[3]);
    } else {
        const int bb = b - NN * CHUNKS;                 // [0, NB)
        if (bb == 0 && tid == 0) {
            unsigned* bar = (unsigned*)(ws + OFF_BAR);
            __hip_atomic_store(&bar[0], 0u, __ATOMIC_RELAXED, __HIP_MEMORY_SCOPE_AGENT);
            __hip_atomic_store(&bar[1], 0u, __ATOMIC_RELAXED, __HIP_MEMORY_SCOPE_AGENT);
        }
        for (int i = tid; i < 4 * 3 * NN; i += 256) ((double*)dp)[i] = 0.0;
        __syncthreads();
        const int* col = eidx + EE;
#pragma unroll
        for (int i = 0; i < EPT; ++i) {                 // 4 iters
            const int e = bb * EPB + i * 256 + tid;
            const int cl = col[e];
#pragma unroll
            for (int c = 0; c < 3; ++c)
                unsafeAtomicAdd(&dp[wave][c][cl], (double)eattr[e * 3 + c]);
        }
        __syncthreads();
        for (int i = tid; i < 3 * NN; i += 256) {
            const int c = i / NN, j = i % NN;
            ws[OFF_DEGP + bb * (3 * NN) + i] =
                (dp[0][c][j] + dp[1][c][j]) + (dp[2][c][j] + dp[3][c][j]);
        }
    }
}

// ---------------------------------------------------------------------------
// Device-scope barrier for NB co-resident blocks (counters zeroed by K1).
// ---------------------------------------------------------------------------
__device__ __forceinline__ void gbar(unsigned* bar, int idx) {
    __syncthreads();
    if (threadIdx.x == 0) {
        __threadfence();
        __hip_atomic_fetch_add(&bar[idx], 1u, __ATOMIC_ACQ_REL, __HIP_MEMORY_SCOPE_AGENT);
        while (__hip_atomic_load(&bar[idx], __ATOMIC_ACQUIRE, __HIP_MEMORY_SCOPE_AGENT) < (unsigned)NB)
            __builtin_amdgcn_s_sleep(1);
        __threadfence();
    }
    __syncthreads();
}

// ---------------------------------------------------------------------------
// K2 (NB=16 blocks, manual grid barriers): rest of network. Separate kernel
// ON PURPOSE: its ~55 KB LDS would cap the streaming matvec at 2 blocks/CU.
// ---------------------------------------------------------------------------
__global__ __launch_bounds__(256) void k_rest(
    const int* __restrict__ eidx, const float* __restrict__ eattr,
    double* __restrict__ ws,
    const float* __restrict__ b1, const float* __restrict__ W2, const float* __restrict__ b2,
    const float* __restrict__ c1w, const float* __restrict__ c1b,
    const float* __restrict__ c2w, const float* __restrict__ c2b,
    const float* __restrict__ f1W, const float* __restrict__ f1b,
    const float* __restrict__ f2W, const float* __restrict__ f2b,
    const float* __restrict__ f3W, const float* __restrict__ f3b,
    float* __restrict__ out)
{
    __shared__ double sxw[NN];
    __shared__ double sdinv[3][NN];
    __shared__ double sh1[3][NN];
    __shared__ double hp[4][3][NN];
    // final-phase (block 0 only)
    __shared__ double h2f[3][NN];
    __shared__ double z0[3][NN], z1[3][NN];
    __shared__ int    rnk[3][NN];
    __shared__ double c1o[3][3][127];
    __shared__ double p1o[3][3][125];
    __shared__ double c2o[3][123];
    __shared__ double allx[363];
    __shared__ double fc1o[32], fc2o[6];

    const int b = blockIdx.x, tid = threadIdx.x, wave = tid >> 6;
    unsigned* bar = (unsigned*)(ws + OFF_BAR);

    // ---- Prefetch this thread's 4 edge records FIRST: the cold-miss latency
    // overlaps the phase-0 partial reductions below.
    int er[EPT], ec[EPT];
    float ea[EPT][3];
#pragma unroll
    for (int i = 0; i < EPT; ++i) {
        const int e = b * EPB + i * 256 + tid;
        er[i] = eidx[e];
        ec[i] = eidx[EE + e];
        ea[i][0] = eattr[e * 3 + 0];
        ea[i][1] = eattr[e * 3 + 1];
        ea[i][2] = eattr[e * 3 + 2];
    }

    // ---- Phase 0: xw + dinv (redundant per block; L2-warm reads)
    for (int j = tid; j < NN; j += 256) {
        double s = 0.0;
#pragma unroll
        for (int k = 0; k < CHUNKS; ++k) s += ws[OFF_PARTIAL + j * CHUNKS + k];
        sxw[j] = s;
    }
    for (int v = tid; v < 3 * NN; v += 256) {
        double d = 1.0;                                  // self loop weight
#pragma unroll
        for (int k = 0; k < NB; ++k) d += ws[OFF_DEGP + k * (3 * NN) + v];
        ((double*)sdinv)[v] = (d > 0.0) ? 1.0 / sqrt(d) : 0.0;
    }
    for (int i = tid; i < 4 * 3 * NN; i += 256) ((double*)hp)[i] = 0.0;
    __syncthreads();

    // ---- Phase 1: layer-1 aggregation; norms cached in registers
    double enw[EPT][3];
#pragma unroll
    for (int i = 0; i < EPT; ++i) {
        const int r = er[i], cl = ec[i];
        const double xwr = sxw[r];
#pragma unroll
        for (int c = 0; c < 3; ++c) {
            const double nw = sdinv[c][r] * (double)ea[i][c] * sdinv[c][cl];
            enw[i][c] = nw;
            unsafeAtomicAdd(&hp[wave][c][cl], nw * xwr);
        }
    }
    __syncthreads();
    for (int i = tid; i < 3 * NN; i += 256) {
        const int c = i / NN, j = i % NN;
        ws[OFF_H1P + b * (3 * NN) + i] =
            (hp[0][c][j] + hp[1][c][j]) + (hp[2][c][j] + hp[3][c][j]);
    }
    gbar(bar, 0);

    // ---- Phase 2: h1 (redundant per block)
    const double bb1 = (double)b1[0];
    for (int i = tid; i < 3 * NN; i += 256) {
        const int j = i % NN;
        const double dv = ((double*)sdinv)[i];
        double s = dv * dv * sxw[j] + bb1;
#pragma unroll
        for (int k = 0; k < NB; ++k) s += ws[OFF_H1P + k * (3 * NN) + i];
        ((double*)sh1)[i] = s;
    }
    for (int i = tid; i < 4 * 3 * NN; i += 256) ((double*)hp)[i] = 0.0;
    __syncthreads();

    // ---- Phase 3: layer-2 aggregation (same edges; register-cached norms)
    const double w2 = (double)W2[0];
#pragma unroll
    for (int i = 0; i < EPT; ++i) {
        const int r = er[i], cl = ec[i];
#pragma unroll
        for (int c = 0; c < 3; ++c)
            unsafeAtomicAdd(&hp[wave][c][cl], enw[i][c] * (sh1[c][r] * w2));
    }
    __syncthreads();
    for (int i = tid; i < 3 * NN; i += 256) {
        const int c = i / NN, j = i % NN;
        ws[OFF_H2P + b * (3 * NN) + i] =
            (hp[0][c][j] + hp[1][c][j]) + (hp[2][c][j] + hp[3][c][j]);
    }
    gbar(bar, 1);

    // ---- Phase 4: block 0 finishes the network
    if (b != 0) return;

    const double bb2 = (double)b2[0];
    for (int i = tid; i < 3 * NN; i += 256) {
        const int j = i % NN;
        const double dv = ((double*)sdinv)[i];
        double s = dv * dv * (((double*)sh1)[i] * w2) + bb2;
#pragma unroll
        for (int k = 0; k < NB; ++k) s += ws[OFF_H2P + k * (3 * NN) + i];
        ((double*)h2f)[i] = s;
    }
    __syncthreads();

    // SortPool: stable argsort of -h2 (descending, ties by index), k = N
    for (int i = tid; i < 3 * NN; i += 256) {
        const int c = i / NN, j = i % NN;
        const double v = h2f[c][j];
        int rk = 0;
        for (int q = 0; q < NN; ++q) {
            const double u = h2f[c][q];
            rk += (u > v) || (u == v && q < j);
        }
        rnk[c][j] = rk;
    }
    __syncthreads();
    for (int i = tid; i < 3 * NN; i += 256) {
        const int c = i / NN, j = i % NN;
        const int rk = rnk[c][j];
        z0[c][rk] = sh1[c][j];
        z1[c][rk] = h2f[c][j];
    }
    __syncthreads();

    // conv1 (in=2,out=3,k=3, VALID) -> 127
    for (int i = tid; i < 3 * 3 * 127; i += 256) {
        const int c = i / (3 * 127), rem = i % (3 * 127), o = rem / 127, p = rem % 127;
        double s = (double)c1b[o];
#pragma unroll
        for (int k = 0; k < 3; ++k) {
            s += (double)c1w[(o * 2 + 0) * 3 + k] * z0[c][p + k];
            s += (double)c1w[(o * 2 + 1) * 3 + k] * z1[c][p + k];
        }
        c1o[c][o][p] = s;
    }
    __syncthreads();
    for (int i = tid; i < 3 * 3 * 125; i += 256) {
        const int c = i / (3 * 125), rem = i % (3 * 125), o = rem / 125, p = rem % 125;
        p1o[c][o][p] = fmax(c1o[c][o][p], fmax(c1o[c][o][p + 1], c1o[c][o][p + 2]));
    }
    __syncthreads();
    for (int i = tid; i < 3 * 123; i += 256) {
        const int c = i / 123, p = i % 123;
        double s = (double)c2b[0];
#pragma unroll
        for (int ic = 0; ic < 3; ++ic)
#pragma unroll
            for (int k = 0; k < 3; ++k)
                s += (double)c2w[ic * 3 + k] * p1o[c][ic][p + k];
        c2o[c][p] = s;
    }
    __syncthreads();
    for (int i = tid; i < 3 * 121; i += 256) {
        const int c = i / 121, p = i % 121;
        allx[c * 121 + p] = fmax(c2o[c][p], fmax(c2o[c][p + 1], c2o[c][p + 2]));
    }
    __syncthreads();

    // fc1: 363 -> 32, ELU (8 lanes per output, aligned subgroups)
    {
        const int j = tid >> 3, t = tid & 7;
        double s = 0.0;
        for (int i = t; i < 363; i += 8) s += allx[i] * (double)f1W[i * 32 + j];
        s += __shfl_down(s, 4, 8);
        s += __shfl_down(s, 2, 8);
        s += __shfl_down(s, 1, 8);
        if (t == 0) {
            s += (double)f1b[j];
            fc1o[j] = (s > 0.0) ? s : expm1(s);
        }
    }
    __syncthreads();
    if (tid < 6) {
        double s = (double)f2b[tid];
        for (int i = 0; i < 32; ++i) s += fc1o[i] * (double)f2W[i * 6 + tid];
        fc2o[tid] = (s > 0.0) ? s : expm1(s);
    }
    __syncthreads();
    if (tid < 2) {
        double s = (double)f3b[tid];
        for (int i = 0; i < 6; ++i) s += fc2o[i] * (double)f3W[i * 2 + tid];
        out[tid] = (float)s;
    }
}

extern "C" void kernel_launch(void* const* d_in, const int* in_sizes, int n_in,
                              void* d_out, int out_size, void* d_ws, size_t ws_size,
                              hipStream_t stream) {
    const float* x    = (const float*)d_in[0];
    const int*   eidx = (const int*)d_in[1];
    const float* eattr= (const float*)d_in[2];
    const float* g1W  = (const float*)d_in[3];
    const float* g1b  = (const float*)d_in[4];
    const float* g2W  = (const float*)d_in[5];
    const float* g2b  = (const float*)d_in[6];
    const float* c1w  = (const float*)d_in[7];
    const float* c1b  = (const float*)d_in[8];
    const float* c2w  = (const float*)d_in[9];
    const float* c2b  = (const float*)d_in[10];
    const float* f1W  = (const float*)d_in[11];
    const float* f1b  = (const float*)d_in[12];
    const float* f2W  = (const float*)d_in[13];
    const float* f2b  = (const float*)d_in[14];
    const float* f3W  = (const float*)d_in[15];
    const float* f3b  = (const float*)d_in[16];
    float* out = (float*)d_out;
    double* ws = (double*)d_ws;

    k_matvec<<<NN * CHUNKS + NB, 256, 0, stream>>>(x, g1W, eidx, eattr, ws);
    k_rest<<<NB, 256, 0, stream>>>(eidx, eattr, ws,
                                   g1b, g2W, g2b, c1w, c1b, c2w, c2b,
                                   f1W, f1b, f2W, f2b, f3W, f3b, out);
}